// Round 4
// baseline (291.202 us; speedup 1.0000x reference)
//
#include <hip/hip_runtime.h>

typedef __attribute__((ext_vector_type(8))) short short8;
typedef __attribute__((ext_vector_type(4))) float f32x4;
typedef __attribute__((ext_vector_type(4))) unsigned int u32x4;
typedef unsigned short ushort_t;

constexpr int B   = 4;
constexpr int C   = 256;
constexpr int H   = 64;
constexpr int W   = 64;
constexpr int HW  = H * W;          // 4096
constexpr int OCH = 256;
constexpr int KT  = 9 * C;          // 2304, k order: k = tap*256 + c
constexpr int NHS = KT / 32;        // 72 half-steps (MFMA K=32)
constexpr int NOUT = KT / 64;       // 36 outer steps (64 k each)

__device__ __forceinline__ ushort_t f2bf(float f) {
    unsigned u = __float_as_uint(f);
    u += 0x7FFF + ((u >> 16) & 1);      // RNE
    return (ushort_t)(u >> 16);
}

// ---------------------------------------------------------------------------
// K0: xtP[bl][y][x][c] (bf16) <- x[pbase+bl][c][y][x] (f32), bl in {0,1}.
// ---------------------------------------------------------------------------
__global__ __launch_bounds__(256) void transpose_pair(
    const float* __restrict__ x, ushort_t* __restrict__ xtP, int pbase)
{
    __shared__ float sT[64][65];
    int blk = blockIdx.x;            // 2*64*4 = 512
    int cg  = blk & 3;               // channel group of 64
    int y   = (blk >> 2) & 63;
    int bl  = blk >> 8;              // 0..1
    int b   = pbase + bl;
    int t   = threadIdx.x;
    int col = t & 63, r4 = t >> 6;

    const float* xp = x + (((size_t)b * C + cg * 64) * H + y) * W;
    #pragma unroll
    for (int i = 0; i < 16; ++i) {
        int cl = i * 4 + r4;
        sT[cl][col] = xp[(size_t)cl * HW + col];
    }
    __syncthreads();
    ushort_t* op = xtP + (((size_t)bl * H + y) * W) * C + cg * 64;
    #pragma unroll
    for (int i = 0; i < 16; ++i) {
        int xl = i * 4 + r4;
        op[(size_t)xl * C + col] = f2bf(sT[col][xl]);
    }
}

// ---------------------------------------------------------------------------
// K1: pack w_def into bf16 A-fragment order (validated round 2/3).
//   wPack[((ks*16 + gt)*64 + lane)*8 + j] = bf16(w_def[o][c][tap])
//   o = gt*16 + (lane&15);  k = ks*32 + (lane>>4)*8 + j; tap = k>>8; c = k&255
// ---------------------------------------------------------------------------
__global__ __launch_bounds__(256) void pack_w(
    const float* __restrict__ w_def, ushort_t* __restrict__ wPack)
{
    int tid = blockIdx.x * 256 + threadIdx.x;     // 72*16*64 = 73728
    if (tid >= NHS * 16 * 64) return;
    int lane = tid & 63;
    int o = ((tid >> 6) & 15) * 16 + (lane & 15);
    int kbase = (tid >> 10) * 32 + (lane >> 4) * 8;
    union { ushort_t u[8]; short8 v; } pk;
    #pragma unroll
    for (int j = 0; j < 8; ++j) {
        int kidx = kbase + j;
        int c = kidx & 255, tap = kidx >> 8;
        pk.u[j] = f2bf(w_def[((size_t)o * C + c) * 9 + tap]);
    }
    *(short8*)(wPack + (size_t)tid * 8) = pk.v;
}

// ---------------------------------------------------------------------------
// K2: wOffT[tap][oc][c] = w_off[oc][c][tap]  (f32)
// ---------------------------------------------------------------------------
__global__ __launch_bounds__(256) void pack_woff(
    const float* __restrict__ w_off, float* __restrict__ wOffT)
{
    int idx = blockIdx.x * 256 + threadIdx.x;     // 9*18*256 = 41472
    if (idx >= 9 * 18 * 256) return;
    int c = idx & 255;
    int oc = (idx >> 8) % 18;
    int tap = idx / (18 * 256);
    wOffT[idx] = w_off[((size_t)oc * C + c) * 9 + tap];
}

// ---------------------------------------------------------------------------
// K3: offset conv for one batch pair. Block (bl,ho), 512 thr; wave g covers
// channels [g*32, g*32+32); LDS reduce across waves; write offP[bl][oc][ho][px].
// (Identical math to round-3's validated fused prologue.)
// ---------------------------------------------------------------------------
__global__ __launch_bounds__(512) void offconv_pair(
    const ushort_t* __restrict__ xtP, const float* __restrict__ wOffT,
    float* __restrict__ offP)
{
    __shared__ float sPart[8][64][18];            // 36.9 KB

    int orig = blockIdx.x;
    int r = ((orig & 7) << 4) | (orig >> 3);      // XCD swizzle, 128 blocks
    int bl = r >> 6, ho = r & 63;
    int tid = threadIdx.x;
    int lane = tid & 63, wv = tid >> 6;
    int gs = __builtin_amdgcn_readfirstlane(wv);
    int px = lane;

    const ushort_t* xtb = xtP + (size_t)bl * HW * C;

    float acc[18];
    #pragma unroll
    for (int oc = 0; oc < 18; ++oc) acc[oc] = 0.f;

    #pragma unroll 1
    for (int tap = 0; tap < 9; ++tap) {
        int ky = tap / 3, kx = tap - ky * 3;
        int y  = ho - 1 + ky;
        int xx = px - 1 + kx;
        bool ok = ((unsigned)y < 64u) && ((unsigned)xx < 64u);
        int yc = min(max(y, 0), 63), xc = min(max(xx, 0), 63);
        const ushort_t* src = xtb + ((size_t)(yc * 64 + xc)) * C + gs * 32;

        float v[32];
        #pragma unroll
        for (int q = 0; q < 4; ++q) {
            u32x4 raw = *(const u32x4*)(src + q * 8);
            #pragma unroll
            for (int j = 0; j < 4; ++j) {
                unsigned u = ok ? raw[j] : 0u;
                v[q * 8 + j * 2]     = __uint_as_float(u << 16);
                v[q * 8 + j * 2 + 1] = __uint_as_float(u & 0xffff0000u);
            }
        }
        const float* wrow = wOffT + ((size_t)tap * 18) * 256 + gs * 32;
        #pragma unroll
        for (int oc = 0; oc < 18; ++oc) {
            const float* wr = wrow + oc * 256;
            #pragma unroll
            for (int cc = 0; cc < 32; ++cc)
                acc[oc] = fmaf(v[cc], wr[cc], acc[oc]);
        }
    }
    float* sp = &sPart[wv][px][0];
    #pragma unroll
    for (int oc = 0; oc < 18; ++oc) sp[oc] = acc[oc];
    __syncthreads();

    for (int idx = tid; idx < 18 * 64; idx += 512) {
        int oc = idx >> 6, p2 = idx & 63;
        float s = 0.f;
        #pragma unroll
        for (int g2 = 0; g2 < 8; ++g2) s += sPart[g2][p2][oc];
        offP[(((size_t)bl * 18 + oc) * 64 + ho) * 64 + p2] = s;
    }
}

// ---------------------------------------------------------------------------
// K4: bilinear sample + bf16 MFMA GEMM for one batch pair.
// Block (bl,ho,ohalf): 256 thr (4 waves); wave wv owns o-range
// ohalf*128 + wv*32, all 64 px. 36 K-steps of 64; staging thread covers
// 8+8 channels of one px (16B gathers from xtP), reg-prefetched one step.
// ---------------------------------------------------------------------------
__global__ __launch_bounds__(256) void deform_pair(
    const ushort_t* __restrict__ xtP, const float* __restrict__ offP,
    const ushort_t* __restrict__ wPack, float* __restrict__ out, int pbase)
{
    __shared__ __align__(16) ushort_t sS[2][8][65][8];   // 16.6 KB (px-padded)
    __shared__ float sOff[18][64];                       // 4.6 KB

    int orig = blockIdx.x;
    int r = ((orig & 7) << 5) | (orig >> 3);   // XCD swizzle, 256 blocks
    int bl = r >> 7, ho = (r >> 1) & 63, ohalf = r & 1;
    int tid = threadIdx.x;
    int lane = tid & 63, wv = tid >> 6;        // 4 waves
    int px = lane;

    const ushort_t* xtb = xtP + (size_t)bl * HW * C;

    // load this row's offsets
    for (int idx = tid; idx < 18 * 64; idx += 256) {
        int oc = idx >> 6, p2 = idx & 63;
        sOff[oc][p2] = offP[(((size_t)bl * 18 + oc) * 64 + ho) * 64 + p2];
    }
    __syncthreads();

    f32x4 acc2[2][4];
    #pragma unroll
    for (int i = 0; i < 2; ++i)
        #pragma unroll
        for (int j = 0; j < 4; ++j) acc2[i][j] = (f32x4){0.f, 0.f, 0.f, 0.f};

    float w00 = 0.f, w01 = 0.f, w10 = 0.f, w11 = 0.f;
    int o00 = 0, o01 = 0, o10 = 0, o11 = 0;
    u32x4 L[8];

    auto make_params = [&](int tap) {
        int ky = tap / 3, kx = tap - ky * 3;
        float offy = sOff[2 * tap][px];
        float offx = sOff[2 * tap + 1][px];
        float py  = offy + (float)(ho - 1 + ky);
        float pxf = offx + (float)(px - 1 + kx);
        float y0f = floorf(py), x0f = floorf(pxf);
        float wy1 = py - y0f, wx1 = pxf - x0f;
        float wy0 = 1.f - wy1, wx0 = 1.f - wx1;
        int y0 = (int)y0f, x0 = (int)x0f;
        int y1 = y0 + 1, x1 = x0 + 1;
        float vy0 = ((unsigned)y0 < 64u) ? 1.f : 0.f;
        float vy1 = ((unsigned)y1 < 64u) ? 1.f : 0.f;
        float vx0 = ((unsigned)x0 < 64u) ? 1.f : 0.f;
        float vx1 = ((unsigned)x1 < 64u) ? 1.f : 0.f;
        int y0c = min(max(y0, 0), 63), y1c = min(max(y1, 0), 63);
        int x0c = min(max(x0, 0), 63), x1c = min(max(x1, 0), 63);
        o00 = (y0c * 64 + x0c) * C; o01 = (y0c * 64 + x1c) * C;
        o10 = (y1c * 64 + x0c) * C; o11 = (y1c * 64 + x1c) * C;
        w00 = wy0 * wx0 * vy0 * vx0; w01 = wy0 * wx1 * vy0 * vx1;
        w10 = wy1 * wx0 * vy1 * vx0; w11 = wy1 * wx1 * vy1 * vx1;
    };

    auto issue = [&](int t) {   // gather (8+8) channels x 4 neighbors
        const ushort_t* p = xtb + ((t & 3) * 64 + wv * 8);
        L[0] = *(const u32x4*)(p + o00);
        L[1] = *(const u32x4*)(p + o01);
        L[2] = *(const u32x4*)(p + o10);
        L[3] = *(const u32x4*)(p + o11);
        const ushort_t* p2 = p + 32;
        L[4] = *(const u32x4*)(p2 + o00);
        L[5] = *(const u32x4*)(p2 + o01);
        L[6] = *(const u32x4*)(p2 + o10);
        L[7] = *(const u32x4*)(p2 + o11);
    };

    auto blendwrite = [&](int t) {
        #pragma unroll
        for (int q = 0; q < 2; ++q) {
            unsigned pk[4];
            #pragma unroll
            for (int j = 0; j < 4; ++j) {
                float f0l = __uint_as_float(L[q * 4 + 0][j] << 16);
                float f0h = __uint_as_float(L[q * 4 + 0][j] & 0xffff0000u);
                float f1l = __uint_as_float(L[q * 4 + 1][j] << 16);
                float f1h = __uint_as_float(L[q * 4 + 1][j] & 0xffff0000u);
                float f2l = __uint_as_float(L[q * 4 + 2][j] << 16);
                float f2h = __uint_as_float(L[q * 4 + 2][j] & 0xffff0000u);
                float f3l = __uint_as_float(L[q * 4 + 3][j] << 16);
                float f3h = __uint_as_float(L[q * 4 + 3][j] & 0xffff0000u);
                float lo = fmaf(w00, f0l, fmaf(w01, f1l, fmaf(w10, f2l, w11 * f3l)));
                float hi = fmaf(w00, f0h, fmaf(w01, f1h, fmaf(w10, f2h, w11 * f3h)));
                asm("v_cvt_pk_bf16_f32 %0, %1, %2" : "=v"(pk[j]) : "v"(lo), "v"(hi));
            }
            u32x4 wvec = (u32x4){pk[0], pk[1], pk[2], pk[3]};
            *(u32x4*)&sS[t & 1][wv + q * 4][lane][0] = wvec;
        }
    };

    make_params(0);
    issue(0);

    int gt0 = ohalf * 8 + wv * 2;
    #pragma unroll 1
    for (int t = 0; t < NOUT; ++t) {
        blendwrite(t);
        if (t + 1 < NOUT) {
            if (((t + 1) & 3) == 0) make_params((t + 1) >> 2);
            issue(t + 1);
        }
        __syncthreads();

        // A fragments for half-steps 2t (h=0) and 2t+1 (h=1), o-tiles gt0,gt0+1
        const short8* wp = (const short8*)wPack + ((size_t)(2 * t) * 16 + gt0) * 64 + lane;
        short8 aF00 = wp[0];
        short8 aF01 = wp[64];
        short8 aF10 = wp[1024];
        short8 aF11 = wp[1088];

        #pragma unroll
        for (int h = 0; h < 2; ++h) {
            short8 aA = h ? aF10 : aF00;
            short8 aB = h ? aF11 : aF01;
            #pragma unroll
            for (int pt = 0; pt < 4; ++pt) {
                short8 bF = *(const short8*)&sS[t & 1][h * 4 + (lane >> 4)][pt * 16 + (lane & 15)][0];
                acc2[0][pt] = __builtin_amdgcn_mfma_f32_16x16x32_bf16(aA, bF, acc2[0][pt], 0, 0, 0);
                acc2[1][pt] = __builtin_amdgcn_mfma_f32_16x16x32_bf16(aB, bF, acc2[1][pt], 0, 0, 0);
            }
        }
    }

    // epilogue: D[row=(l>>4)*4+j][col=l&15]
    int b = pbase + bl;
    #pragma unroll
    for (int ot = 0; ot < 2; ++ot) {
        int o = ohalf * 128 + wv * 32 + ot * 16 + (lane >> 4) * 4;
        #pragma unroll
        for (int pt = 0; pt < 4; ++pt) {
            int pxx = pt * 16 + (lane & 15);
            #pragma unroll
            for (int j = 0; j < 4; ++j)
                out[(((size_t)b * OCH + (o + j)) * H + ho) * W + pxx] = acc2[ot][pt][j];
        }
    }
}

// ---------------------------------------------------------------------------
extern "C" void kernel_launch(void* const* d_in, const int* in_sizes, int n_in,
                              void* d_out, int out_size, void* d_ws, size_t ws_size,
                              hipStream_t stream)
{
    const float* x     = (const float*)d_in[0];
    const float* w_off = (const float*)d_in[1];
    const float* w_def = (const float*)d_in[2];
    float* out = (float*)d_out;

    // ws: xtPair[2*4096*256 bf16 = 4.19MB] | wPack[1.18MB] | wOffT[166KB] | offP[590KB]
    // total 6,129,664 B  (< round-2-proven 7,077,888 B budget)
    ushort_t* xtP   = (ushort_t*)d_ws;
    ushort_t* wPack = xtP + (size_t)2 * HW * C;
    float*    wOffT = (float*)(wPack + (size_t)NHS * 16 * 64 * 8);
    float*    offP  = wOffT + 9 * 18 * 256;

    pack_w<<<(NHS * 16 * 64 + 255) / 256, 256, 0, stream>>>(w_def, wPack);
    pack_woff<<<(9 * 18 * 256 + 255) / 256, 256, 0, stream>>>(w_off, wOffT);

    for (int pr = 0; pr < 2; ++pr) {
        transpose_pair<<<512, 256, 0, stream>>>(x, xtP, pr * 2);
        offconv_pair<<<128, 512, 0, stream>>>(xtP, wOffT, offP);
        deform_pair<<<256, 256, 0, stream>>>(xtP, offP, wPack, out, pr * 2);
    }
}

// Round 5
// 162.085 us; speedup vs baseline: 1.7966x; 1.7966x over previous
//
#include <hip/hip_runtime.h>

typedef __attribute__((ext_vector_type(8))) short short8;
typedef __attribute__((ext_vector_type(4))) float f32x4;
typedef __attribute__((ext_vector_type(4))) unsigned int u32x4;
typedef unsigned short ushort_t;

constexpr int B   = 4;
constexpr int C   = 256;
constexpr int H   = 64;
constexpr int W   = 64;
constexpr int HW  = H * W;          // 4096
constexpr int OCH = 256;
constexpr int KT  = 9 * C;          // 2304, k order: k = tap*256 + c
constexpr int NHS = KT / 32;        // 72 half-steps (MFMA K=32)
constexpr int NOUT = KT / 64;       // 36 outer steps (64 k each)

__device__ __forceinline__ ushort_t f2bf(float f) {
    unsigned u = __float_as_uint(f);
    u += 0x7FFF + ((u >> 16) & 1);      // RNE
    return (ushort_t)(u >> 16);
}

// ---------------------------------------------------------------------------
// K0: xtP[bl][y][x][c] (bf16) <- x[pbase+bl][c][y][x] (f32), bl in {0,1}.
// ---------------------------------------------------------------------------
__global__ __launch_bounds__(256) void transpose_pair(
    const float* __restrict__ x, ushort_t* __restrict__ xtP, int pbase)
{
    __shared__ float sT[64][65];
    int blk = blockIdx.x;            // 2*64*4 = 512
    int cg  = blk & 3;               // channel group of 64
    int y   = (blk >> 2) & 63;
    int bl  = blk >> 8;              // 0..1
    int b   = pbase + bl;
    int t   = threadIdx.x;
    int col = t & 63, r4 = t >> 6;

    const float* xp = x + (((size_t)b * C + cg * 64) * H + y) * W;
    #pragma unroll
    for (int i = 0; i < 16; ++i) {
        int cl = i * 4 + r4;
        sT[cl][col] = xp[(size_t)cl * HW + col];
    }
    __syncthreads();
    ushort_t* op = xtP + (((size_t)bl * H + y) * W) * C + cg * 64;
    #pragma unroll
    for (int i = 0; i < 16; ++i) {
        int xl = i * 4 + r4;
        op[(size_t)xl * C + col] = f2bf(sT[col][xl]);
    }
}

// ---------------------------------------------------------------------------
// K1: pack w_def into bf16 A-fragment order (validated rounds 2-4).
//   wPack[((ks*16 + gt)*64 + lane)*8 + j] = bf16(w_def[o][c][tap])
//   o = gt*16 + (lane&15);  k = ks*32 + (lane>>4)*8 + j; tap = k>>8; c = k&255
// ---------------------------------------------------------------------------
__global__ __launch_bounds__(256) void pack_w(
    const float* __restrict__ w_def, ushort_t* __restrict__ wPack)
{
    int tid = blockIdx.x * 256 + threadIdx.x;     // 72*16*64 = 73728
    if (tid >= NHS * 16 * 64) return;
    int lane = tid & 63;
    int o = ((tid >> 6) & 15) * 16 + (lane & 15);
    int kbase = (tid >> 10) * 32 + (lane >> 4) * 8;
    union { ushort_t u[8]; short8 v; } pk;
    #pragma unroll
    for (int j = 0; j < 8; ++j) {
        int kidx = kbase + j;
        int c = kidx & 255, tap = kidx >> 8;
        pk.u[j] = f2bf(w_def[((size_t)o * C + c) * 9 + tap]);
    }
    *(short8*)(wPack + (size_t)tid * 8) = pk.v;
}

// ---------------------------------------------------------------------------
// K2: pack w_off into bf16 A-fragment order, M padded 18 -> 32.
//   wOffA[((ks*2 + gt)*64 + lane)*8 + j] = bf16(w_off[o][c][tap]) or 0 if o>=18
//   o = gt*16 + (lane&15);  k = ks*32 + (lane>>4)*8 + j; tap = k>>8; c = k&255
// ---------------------------------------------------------------------------
__global__ __launch_bounds__(256) void pack_woffA(
    const float* __restrict__ w_off, ushort_t* __restrict__ wOffA)
{
    int tid = blockIdx.x * 256 + threadIdx.x;     // 72*2*64 = 9216
    if (tid >= NHS * 2 * 64) return;
    int lane = tid & 63;
    int o = ((tid >> 6) & 1) * 16 + (lane & 15);
    int kbase = (tid >> 7) * 32 + (lane >> 4) * 8;
    union { ushort_t u[8]; short8 v; } pk;
    #pragma unroll
    for (int j = 0; j < 8; ++j) {
        int kidx = kbase + j;
        int c = kidx & 255, tap = kidx >> 8;
        pk.u[j] = (o < 18) ? f2bf(w_off[((size_t)o * C + c) * 9 + tap]) : (ushort_t)0;
    }
    *(short8*)(wOffA + (size_t)tid * 8) = pk.v;
}

// ---------------------------------------------------------------------------
// K3: offset conv via MFMA.  Grid (bl,ho,kg) = 256 blocks, 256 thr (4 waves).
// Wave wv owns px-tile [wv*16, wv*16+16).  B-fragments are direct contiguous
// 16B loads from xtP (fixed grid taps -> no gather), masked per-lane for OOB.
// kg splits K at tap granularity: kg0 taps 0..3, kg1 taps 4..8.
// No LDS, no barriers.  offPart[kg][bl][oc][ho][px] partials.
// ---------------------------------------------------------------------------
__global__ __launch_bounds__(256) void offconv_mfma(
    const ushort_t* __restrict__ xtP, const ushort_t* __restrict__ wOffA,
    float* __restrict__ offPart)
{
    int orig = blockIdx.x;
    int r = ((orig & 7) << 5) | (orig >> 3);   // XCD swizzle, 256 blocks
    int bl = r >> 7, ho = (r >> 1) & 63, kg = r & 1;
    int tid = threadIdx.x;
    int lane = tid & 63, wv = tid >> 6;
    int px = wv * 16 + (lane & 15);
    int cseg = (lane >> 4) * 8;

    const ushort_t* xtb = xtP + (size_t)bl * HW * C;
    const short8*   wA  = (const short8*)wOffA;

    f32x4 acc[2];
    acc[0] = (f32x4){0.f, 0.f, 0.f, 0.f};
    acc[1] = (f32x4){0.f, 0.f, 0.f, 0.f};

    int tap0 = kg ? 4 : 0;
    int tap1 = kg ? 9 : 4;

    #pragma unroll 1
    for (int tap = tap0; tap < tap1; ++tap) {
        int ky = tap / 3, kx = tap - ky * 3;
        int y  = ho - 1 + ky;
        int xx = px - 1 + kx;
        bool ok = ((unsigned)y < 64u) && ((unsigned)xx < 64u);
        unsigned msk = ok ? 0xffffffffu : 0u;
        int yc = min(max(y, 0), 63), xc = min(max(xx, 0), 63);
        const ushort_t* srcb = xtb + (size_t)(yc * 64 + xc) * C + cseg;

        #pragma unroll
        for (int cs = 0; cs < 8; ++cs) {
            union { u32x4 u; short8 s; } bv;
            bv.u = *(const u32x4*)(srcb + cs * 32);
            bv.u[0] &= msk; bv.u[1] &= msk; bv.u[2] &= msk; bv.u[3] &= msk;
            int ks = tap * 8 + cs;
            short8 aF0 = wA[(size_t)ks * 128 + lane];
            short8 aF1 = wA[(size_t)ks * 128 + 64 + lane];
            acc[0] = __builtin_amdgcn_mfma_f32_16x16x32_bf16(aF0, bv.s, acc[0], 0, 0, 0);
            acc[1] = __builtin_amdgcn_mfma_f32_16x16x32_bf16(aF1, bv.s, acc[1], 0, 0, 0);
        }
    }

    // D[row=(l>>4)*4+j][col=l&15]; only oc<18 stored
    #pragma unroll
    for (int gt = 0; gt < 2; ++gt) {
        #pragma unroll
        for (int j = 0; j < 4; ++j) {
            int oc = gt * 16 + (lane >> 4) * 4 + j;
            if (oc < 18)
                offPart[(((size_t)kg * 2 + bl) * 18 + oc) * HW + ho * 64 + px] = acc[gt][j];
        }
    }
}

// ---------------------------------------------------------------------------
// K4: bilinear sample + bf16 MFMA GEMM for one batch pair (round-4 validated).
// Only change: sOff load sums the two K-partials of offPart.
// ---------------------------------------------------------------------------
__global__ __launch_bounds__(256) void deform_pair(
    const ushort_t* __restrict__ xtP, const float* __restrict__ offPart,
    const ushort_t* __restrict__ wPack, float* __restrict__ out, int pbase)
{
    __shared__ __align__(16) ushort_t sS[2][8][65][8];   // 16.6 KB (px-padded)
    __shared__ float sOff[18][64];                       // 4.6 KB

    int orig = blockIdx.x;
    int r = ((orig & 7) << 5) | (orig >> 3);   // XCD swizzle, 256 blocks
    int bl = r >> 7, ho = (r >> 1) & 63, ohalf = r & 1;
    int tid = threadIdx.x;
    int lane = tid & 63, wv = tid >> 6;        // 4 waves
    int px = lane;

    const ushort_t* xtb = xtP + (size_t)bl * HW * C;

    // load this row's offsets (sum of the two K-split partials)
    for (int idx = tid; idx < 18 * 64; idx += 256) {
        int oc = idx >> 6, p2 = idx & 63;
        size_t base = ((size_t)bl * 18 + oc) * HW + ho * 64 + p2;
        sOff[oc][p2] = offPart[base] + offPart[(size_t)2 * 18 * HW + base];
    }
    __syncthreads();

    f32x4 acc2[2][4];
    #pragma unroll
    for (int i = 0; i < 2; ++i)
        #pragma unroll
        for (int j = 0; j < 4; ++j) acc2[i][j] = (f32x4){0.f, 0.f, 0.f, 0.f};

    float w00 = 0.f, w01 = 0.f, w10 = 0.f, w11 = 0.f;
    int o00 = 0, o01 = 0, o10 = 0, o11 = 0;
    u32x4 L[8];

    auto make_params = [&](int tap) {
        int ky = tap / 3, kx = tap - ky * 3;
        float offy = sOff[2 * tap][px];
        float offx = sOff[2 * tap + 1][px];
        float py  = offy + (float)(ho - 1 + ky);
        float pxf = offx + (float)(px - 1 + kx);
        float y0f = floorf(py), x0f = floorf(pxf);
        float wy1 = py - y0f, wx1 = pxf - x0f;
        float wy0 = 1.f - wy1, wx0 = 1.f - wx1;
        int y0 = (int)y0f, x0 = (int)x0f;
        int y1 = y0 + 1, x1 = x0 + 1;
        float vy0 = ((unsigned)y0 < 64u) ? 1.f : 0.f;
        float vy1 = ((unsigned)y1 < 64u) ? 1.f : 0.f;
        float vx0 = ((unsigned)x0 < 64u) ? 1.f : 0.f;
        float vx1 = ((unsigned)x1 < 64u) ? 1.f : 0.f;
        int y0c = min(max(y0, 0), 63), y1c = min(max(y1, 0), 63);
        int x0c = min(max(x0, 0), 63), x1c = min(max(x1, 0), 63);
        o00 = (y0c * 64 + x0c) * C; o01 = (y0c * 64 + x1c) * C;
        o10 = (y1c * 64 + x0c) * C; o11 = (y1c * 64 + x1c) * C;
        w00 = wy0 * wx0 * vy0 * vx0; w01 = wy0 * wx1 * vy0 * vx1;
        w10 = wy1 * wx0 * vy1 * vx0; w11 = wy1 * wx1 * vy1 * vx1;
    };

    auto issue = [&](int t) {   // gather (8+8) channels x 4 neighbors
        const ushort_t* p = xtb + ((t & 3) * 64 + wv * 8);
        L[0] = *(const u32x4*)(p + o00);
        L[1] = *(const u32x4*)(p + o01);
        L[2] = *(const u32x4*)(p + o10);
        L[3] = *(const u32x4*)(p + o11);
        const ushort_t* p2 = p + 32;
        L[4] = *(const u32x4*)(p2 + o00);
        L[5] = *(const u32x4*)(p2 + o01);
        L[6] = *(const u32x4*)(p2 + o10);
        L[7] = *(const u32x4*)(p2 + o11);
    };

    auto blendwrite = [&](int t) {
        #pragma unroll
        for (int q = 0; q < 2; ++q) {
            unsigned pk[4];
            #pragma unroll
            for (int j = 0; j < 4; ++j) {
                float f0l = __uint_as_float(L[q * 4 + 0][j] << 16);
                float f0h = __uint_as_float(L[q * 4 + 0][j] & 0xffff0000u);
                float f1l = __uint_as_float(L[q * 4 + 1][j] << 16);
                float f1h = __uint_as_float(L[q * 4 + 1][j] & 0xffff0000u);
                float f2l = __uint_as_float(L[q * 4 + 2][j] << 16);
                float f2h = __uint_as_float(L[q * 4 + 2][j] & 0xffff0000u);
                float f3l = __uint_as_float(L[q * 4 + 3][j] << 16);
                float f3h = __uint_as_float(L[q * 4 + 3][j] & 0xffff0000u);
                float lo = fmaf(w00, f0l, fmaf(w01, f1l, fmaf(w10, f2l, w11 * f3l)));
                float hi = fmaf(w00, f0h, fmaf(w01, f1h, fmaf(w10, f2h, w11 * f3h)));
                asm("v_cvt_pk_bf16_f32 %0, %1, %2" : "=v"(pk[j]) : "v"(lo), "v"(hi));
            }
            u32x4 wvec = (u32x4){pk[0], pk[1], pk[2], pk[3]};
            *(u32x4*)&sS[t & 1][wv + q * 4][lane][0] = wvec;
        }
    };

    make_params(0);
    issue(0);

    int gt0 = ohalf * 8 + wv * 2;
    #pragma unroll 1
    for (int t = 0; t < NOUT; ++t) {
        blendwrite(t);
        if (t + 1 < NOUT) {
            if (((t + 1) & 3) == 0) make_params((t + 1) >> 2);
            issue(t + 1);
        }
        __syncthreads();

        // A fragments for half-steps 2t (h=0) and 2t+1 (h=1), o-tiles gt0,gt0+1
        const short8* wp = (const short8*)wPack + ((size_t)(2 * t) * 16 + gt0) * 64 + lane;
        short8 aF00 = wp[0];
        short8 aF01 = wp[64];
        short8 aF10 = wp[1024];
        short8 aF11 = wp[1088];

        #pragma unroll
        for (int h = 0; h < 2; ++h) {
            short8 aA = h ? aF10 : aF00;
            short8 aB = h ? aF11 : aF01;
            #pragma unroll
            for (int pt = 0; pt < 4; ++pt) {
                short8 bF = *(const short8*)&sS[t & 1][h * 4 + (lane >> 4)][pt * 16 + (lane & 15)][0];
                acc2[0][pt] = __builtin_amdgcn_mfma_f32_16x16x32_bf16(aA, bF, acc2[0][pt], 0, 0, 0);
                acc2[1][pt] = __builtin_amdgcn_mfma_f32_16x16x32_bf16(aB, bF, acc2[1][pt], 0, 0, 0);
            }
        }
    }

    // epilogue: D[row=(l>>4)*4+j][col=l&15]
    int b = pbase + bl;
    #pragma unroll
    for (int ot = 0; ot < 2; ++ot) {
        int o = ohalf * 128 + wv * 32 + ot * 16 + (lane >> 4) * 4;
        #pragma unroll
        for (int pt = 0; pt < 4; ++pt) {
            int pxx = pt * 16 + (lane & 15);
            #pragma unroll
            for (int j = 0; j < 4; ++j)
                out[(((size_t)b * OCH + (o + j)) * H + ho) * W + pxx] = acc2[ot][pt][j];
        }
    }
}

// ---------------------------------------------------------------------------
extern "C" void kernel_launch(void* const* d_in, const int* in_sizes, int n_in,
                              void* d_out, int out_size, void* d_ws, size_t ws_size,
                              hipStream_t stream)
{
    const float* x     = (const float*)d_in[0];
    const float* w_off = (const float*)d_in[1];
    const float* w_def = (const float*)d_in[2];
    float* out = (float*)d_out;

    // ws: xtPair[4.19MB] | wPack[1.18MB] | wOffA[147KB] | offPart[1.18MB]
    // total 6,701,056 B  (< round-2-proven 7,077,888 B budget)
    ushort_t* xtP     = (ushort_t*)d_ws;
    ushort_t* wPack   = xtP + (size_t)2 * HW * C;
    ushort_t* wOffA   = wPack + (size_t)NHS * 16 * 64 * 8;
    float*    offPart = (float*)(wOffA + (size_t)NHS * 2 * 64 * 8);

    pack_w<<<(NHS * 16 * 64 + 255) / 256, 256, 0, stream>>>(w_def, wPack);
    pack_woffA<<<(NHS * 2 * 64 + 255) / 256, 256, 0, stream>>>(w_off, wOffA);

    for (int pr = 0; pr < 2; ++pr) {
        transpose_pair<<<512, 256, 0, stream>>>(x, xtP, pr * 2);
        offconv_mfma<<<256, 256, 0, stream>>>(xtP, wOffA, offPart);
        deform_pair<<<256, 256, 0, stream>>>(xtP, offPart, wPack, out, pr * 2);
    }
}

// Round 6
// 127.367 us; speedup vs baseline: 2.2863x; 1.2726x over previous
//
#include <hip/hip_runtime.h>

typedef __attribute__((ext_vector_type(8))) short short8;
typedef __attribute__((ext_vector_type(4))) float f32x4;
typedef __attribute__((ext_vector_type(4))) unsigned int u32x4;
typedef unsigned short ushort_t;

constexpr int B   = 4;
constexpr int C   = 256;
constexpr int H   = 64;
constexpr int W   = 64;
constexpr int HW  = H * W;          // 4096
constexpr int OCH = 256;
constexpr int KT  = 9 * C;          // 2304, k order: k = tap*256 + c
constexpr int NHS = KT / 32;        // 72 half-steps (MFMA K=32)
constexpr int NOUT = KT / 64;       // 36 outer steps (64 k each)

__device__ __forceinline__ ushort_t f2bf(float f) {
    unsigned u = __float_as_uint(f);
    u += 0x7FFF + ((u >> 16) & 1);      // RNE
    return (ushort_t)(u >> 16);
}

// ---------------------------------------------------------------------------
// K0: xtP[bl][y][x][c] (bf16) <- x[pbase+bl][c][y][x] (f32), bl in {0,1}.
// ---------------------------------------------------------------------------
__global__ __launch_bounds__(256) void transpose_pair(
    const float* __restrict__ x, ushort_t* __restrict__ xtP, int pbase)
{
    __shared__ float sT[64][65];
    int blk = blockIdx.x;            // 2*64*4 = 512
    int cg  = blk & 3;               // channel group of 64
    int y   = (blk >> 2) & 63;
    int bl  = blk >> 8;              // 0..1
    int b   = pbase + bl;
    int t   = threadIdx.x;
    int col = t & 63, r4 = t >> 6;

    const float* xp = x + (((size_t)b * C + cg * 64) * H + y) * W;
    #pragma unroll
    for (int i = 0; i < 16; ++i) {
        int cl = i * 4 + r4;
        sT[cl][col] = xp[(size_t)cl * HW + col];
    }
    __syncthreads();
    ushort_t* op = xtP + (((size_t)bl * H + y) * W) * C + cg * 64;
    #pragma unroll
    for (int i = 0; i < 16; ++i) {
        int xl = i * 4 + r4;
        op[(size_t)xl * C + col] = f2bf(sT[col][xl]);
    }
}

// ---------------------------------------------------------------------------
// K1: pack w_def into bf16 A-fragment order (validated rounds 2-5).
//   wPack[((ks*16 + gt)*64 + lane)*8 + j] = bf16(w_def[o][c][tap])
//   o = gt*16 + (lane&15);  k = ks*32 + (lane>>4)*8 + j; tap = k>>8; c = k&255
// ---------------------------------------------------------------------------
__global__ __launch_bounds__(256) void pack_w(
    const float* __restrict__ w_def, ushort_t* __restrict__ wPack)
{
    int tid = blockIdx.x * 256 + threadIdx.x;     // 72*16*64 = 73728
    if (tid >= NHS * 16 * 64) return;
    int lane = tid & 63;
    int o = ((tid >> 6) & 15) * 16 + (lane & 15);
    int kbase = (tid >> 10) * 32 + (lane >> 4) * 8;
    union { ushort_t u[8]; short8 v; } pk;
    #pragma unroll
    for (int j = 0; j < 8; ++j) {
        int kidx = kbase + j;
        int c = kidx & 255, tap = kidx >> 8;
        pk.u[j] = f2bf(w_def[((size_t)o * C + c) * 9 + tap]);
    }
    *(short8*)(wPack + (size_t)tid * 8) = pk.v;
}

// ---------------------------------------------------------------------------
// K2: pack w_off into bf16 A-fragment order, M padded 18 -> 32.
// ---------------------------------------------------------------------------
__global__ __launch_bounds__(256) void pack_woffA(
    const float* __restrict__ w_off, ushort_t* __restrict__ wOffA)
{
    int tid = blockIdx.x * 256 + threadIdx.x;     // 72*2*64 = 9216
    if (tid >= NHS * 2 * 64) return;
    int lane = tid & 63;
    int o = ((tid >> 6) & 1) * 16 + (lane & 15);
    int kbase = (tid >> 7) * 32 + (lane >> 4) * 8;
    union { ushort_t u[8]; short8 v; } pk;
    #pragma unroll
    for (int j = 0; j < 8; ++j) {
        int kidx = kbase + j;
        int c = kidx & 255, tap = kidx >> 8;
        pk.u[j] = (o < 18) ? f2bf(w_off[((size_t)o * C + c) * 9 + tap]) : (ushort_t)0;
    }
    *(short8*)(wOffA + (size_t)tid * 8) = pk.v;
}

// ---------------------------------------------------------------------------
// K3: offset conv via MFMA (validated round 5).  Grid (bl,ho,kg) = 256 blocks.
// ---------------------------------------------------------------------------
__global__ __launch_bounds__(256) void offconv_mfma(
    const ushort_t* __restrict__ xtP, const ushort_t* __restrict__ wOffA,
    float* __restrict__ offPart)
{
    int orig = blockIdx.x;
    int r = ((orig & 7) << 5) | (orig >> 3);   // XCD swizzle, 256 blocks
    int bl = r >> 7, ho = (r >> 1) & 63, kg = r & 1;
    int tid = threadIdx.x;
    int lane = tid & 63, wv = tid >> 6;
    int px = wv * 16 + (lane & 15);
    int cseg = (lane >> 4) * 8;

    const ushort_t* xtb = xtP + (size_t)bl * HW * C;
    const short8*   wA  = (const short8*)wOffA;

    f32x4 acc[2];
    acc[0] = (f32x4){0.f, 0.f, 0.f, 0.f};
    acc[1] = (f32x4){0.f, 0.f, 0.f, 0.f};

    int tap0 = kg ? 4 : 0;
    int tap1 = kg ? 9 : 4;

    #pragma unroll 1
    for (int tap = tap0; tap < tap1; ++tap) {
        int ky = tap / 3, kx = tap - ky * 3;
        int y  = ho - 1 + ky;
        int xx = px - 1 + kx;
        bool ok = ((unsigned)y < 64u) && ((unsigned)xx < 64u);
        unsigned msk = ok ? 0xffffffffu : 0u;
        int yc = min(max(y, 0), 63), xc = min(max(xx, 0), 63);
        const ushort_t* srcb = xtb + (size_t)(yc * 64 + xc) * C + cseg;

        #pragma unroll
        for (int cs = 0; cs < 8; ++cs) {
            union { u32x4 u; short8 s; } bv;
            bv.u = *(const u32x4*)(srcb + cs * 32);
            bv.u[0] &= msk; bv.u[1] &= msk; bv.u[2] &= msk; bv.u[3] &= msk;
            int ks = tap * 8 + cs;
            short8 aF0 = wA[(size_t)ks * 128 + lane];
            short8 aF1 = wA[(size_t)ks * 128 + 64 + lane];
            acc[0] = __builtin_amdgcn_mfma_f32_16x16x32_bf16(aF0, bv.s, acc[0], 0, 0, 0);
            acc[1] = __builtin_amdgcn_mfma_f32_16x16x32_bf16(aF1, bv.s, acc[1], 0, 0, 0);
        }
    }

    #pragma unroll
    for (int gt = 0; gt < 2; ++gt) {
        #pragma unroll
        for (int j = 0; j < 4; ++j) {
            int oc = gt * 16 + (lane >> 4) * 4 + j;
            if (oc < 18)
                offPart[(((size_t)kg * 2 + bl) * 18 + oc) * HW + ho * 64 + px] = acc[gt][j];
        }
    }
}

// ---------------------------------------------------------------------------
// K4: bilinear sample + bf16 MFMA GEMM, px-split for occupancy.
// Grid (bl,ho,ohalf,pxh) = 512 blocks of 256 thr (2 blocks/CU, 8 waves/CU).
// Staging identity: px32 = tid&31, kc = tid>>5 (8 kc x 32 px = 256 vectors of
// 8 ch).  Loads for step t+1 issued AFTER the barrier (drain-free, covered by
// MFMA phase); A-fragments prefetched one step ahead.
// ---------------------------------------------------------------------------
__global__ __launch_bounds__(256) void deform_pair(
    const ushort_t* __restrict__ xtP, const float* __restrict__ offPart,
    const ushort_t* __restrict__ wPack, float* __restrict__ out, int pbase)
{
    __shared__ __align__(16) ushort_t sS[2][8][33][8];   // 8.4 KB (px-padded)
    __shared__ float sOff[18][32];                       // 2.3 KB

    int orig = blockIdx.x;
    int r = ((orig & 7) << 6) | (orig >> 3);   // XCD swizzle, 512 blocks
    int bl = r >> 8, ho = (r >> 2) & 63, ohalf = (r >> 1) & 1, pxh = r & 1;
    int tid = threadIdx.x;
    int lane = tid & 63, wv = tid >> 6;        // 4 waves
    int px32 = tid & 31, kc = tid >> 5;        // staging identity
    int px = pxh * 32 + px32;

    const ushort_t* xtb = xtP + (size_t)bl * HW * C;

    // this row's offsets for our px half (sum of the two K-split partials)
    for (int idx = tid; idx < 18 * 32; idx += 256) {
        int oc = idx >> 5, p2 = idx & 31;
        size_t base = ((size_t)bl * 18 + oc) * HW + ho * 64 + pxh * 32 + p2;
        sOff[oc][p2] = offPart[base] + offPart[(size_t)2 * 18 * HW + base];
    }
    __syncthreads();

    f32x4 acc2[2][2];
    #pragma unroll
    for (int i = 0; i < 2; ++i)
        #pragma unroll
        for (int j = 0; j < 2; ++j) acc2[i][j] = (f32x4){0.f, 0.f, 0.f, 0.f};

    float w00 = 0.f, w01 = 0.f, w10 = 0.f, w11 = 0.f;
    int o00 = 0, o01 = 0, o10 = 0, o11 = 0;
    u32x4 L[4];

    auto make_params = [&](int tap) {
        int ky = tap / 3, kx = tap - ky * 3;
        float offy = sOff[2 * tap][px32];
        float offx = sOff[2 * tap + 1][px32];
        float py  = offy + (float)(ho - 1 + ky);
        float pxf = offx + (float)(px - 1 + kx);
        float y0f = floorf(py), x0f = floorf(pxf);
        float wy1 = py - y0f, wx1 = pxf - x0f;
        float wy0 = 1.f - wy1, wx0 = 1.f - wx1;
        int y0 = (int)y0f, x0 = (int)x0f;
        int y1 = y0 + 1, x1 = x0 + 1;
        float vy0 = ((unsigned)y0 < 64u) ? 1.f : 0.f;
        float vy1 = ((unsigned)y1 < 64u) ? 1.f : 0.f;
        float vx0 = ((unsigned)x0 < 64u) ? 1.f : 0.f;
        float vx1 = ((unsigned)x1 < 64u) ? 1.f : 0.f;
        int y0c = min(max(y0, 0), 63), y1c = min(max(y1, 0), 63);
        int x0c = min(max(x0, 0), 63), x1c = min(max(x1, 0), 63);
        o00 = (y0c * 64 + x0c) * C; o01 = (y0c * 64 + x1c) * C;
        o10 = (y1c * 64 + x0c) * C; o11 = (y1c * 64 + x1c) * C;
        w00 = wy0 * wx0 * vy0 * vx0; w01 = wy0 * wx1 * vy0 * vx1;
        w10 = wy1 * wx0 * vy1 * vx0; w11 = wy1 * wx1 * vy1 * vx1;
    };

    auto issue = [&](int t) {   // 8 channels x 4 neighbors for (kc, px)
        const ushort_t* p = xtb + ((t & 3) * 64 + kc * 8);
        L[0] = *(const u32x4*)(p + o00);
        L[1] = *(const u32x4*)(p + o01);
        L[2] = *(const u32x4*)(p + o10);
        L[3] = *(const u32x4*)(p + o11);
    };

    auto blendwrite = [&](int t) {
        unsigned pk[4];
        #pragma unroll
        for (int j = 0; j < 4; ++j) {
            float f0l = __uint_as_float(L[0][j] << 16);
            float f0h = __uint_as_float(L[0][j] & 0xffff0000u);
            float f1l = __uint_as_float(L[1][j] << 16);
            float f1h = __uint_as_float(L[1][j] & 0xffff0000u);
            float f2l = __uint_as_float(L[2][j] << 16);
            float f2h = __uint_as_float(L[2][j] & 0xffff0000u);
            float f3l = __uint_as_float(L[3][j] << 16);
            float f3h = __uint_as_float(L[3][j] & 0xffff0000u);
            float lo = fmaf(w00, f0l, fmaf(w01, f1l, fmaf(w10, f2l, w11 * f3l)));
            float hi = fmaf(w00, f0h, fmaf(w01, f1h, fmaf(w10, f2h, w11 * f3h)));
            asm("v_cvt_pk_bf16_f32 %0, %1, %2" : "=v"(pk[j]) : "v"(lo), "v"(hi));
        }
        u32x4 wvec = (u32x4){pk[0], pk[1], pk[2], pk[3]};
        *(u32x4*)&sS[t & 1][kc][px32][0] = wvec;
    };

    int gt0 = ohalf * 8 + wv * 2;
    const short8* wpB = (const short8*)wPack;
    auto aoff = [&](int t) { return ((size_t)(2 * t) * 16 + gt0) * 64 + lane; };

    make_params(0);
    issue(0);
    size_t a0 = aoff(0);
    short8 aF00 = wpB[a0], aF01 = wpB[a0 + 64];
    short8 aF10 = wpB[a0 + 1024], aF11 = wpB[a0 + 1088];

    #pragma unroll 1
    for (int t = 0; t < NOUT; ++t) {
        blendwrite(t);
        __syncthreads();                       // no vmem in flight: free drain

        bool more = (t + 1 < NOUT);
        short8 nF00, nF01, nF10, nF11;
        if (more) {
            if (((t + 1) & 3) == 0) make_params((t + 1) >> 2);
            issue(t + 1);                      // covered by MFMA below
            size_t an = aoff(t + 1);
            nF00 = wpB[an];  nF01 = wpB[an + 64];
            nF10 = wpB[an + 1024]; nF11 = wpB[an + 1088];
        }

        #pragma unroll
        for (int h = 0; h < 2; ++h) {
            short8 aA = h ? aF10 : aF00;
            short8 aB = h ? aF11 : aF01;
            #pragma unroll
            for (int pt = 0; pt < 2; ++pt) {
                short8 bF = *(const short8*)&sS[t & 1][h * 4 + (lane >> 4)][pt * 16 + (lane & 15)][0];
                acc2[0][pt] = __builtin_amdgcn_mfma_f32_16x16x32_bf16(aA, bF, acc2[0][pt], 0, 0, 0);
                acc2[1][pt] = __builtin_amdgcn_mfma_f32_16x16x32_bf16(aB, bF, acc2[1][pt], 0, 0, 0);
            }
        }
        if (more) { aF00 = nF00; aF01 = nF01; aF10 = nF10; aF11 = nF11; }
    }

    // epilogue: D[row=(l>>4)*4+j][col=l&15]
    int b = pbase + bl;
    #pragma unroll
    for (int ot = 0; ot < 2; ++ot) {
        int o = ohalf * 128 + wv * 32 + ot * 16 + (lane >> 4) * 4;
        #pragma unroll
        for (int pt = 0; pt < 2; ++pt) {
            int pxx = pxh * 32 + pt * 16 + (lane & 15);
            #pragma unroll
            for (int j = 0; j < 4; ++j)
                out[(((size_t)b * OCH + (o + j)) * H + ho) * W + pxx] = acc2[ot][pt][j];
        }
    }
}

// ---------------------------------------------------------------------------
extern "C" void kernel_launch(void* const* d_in, const int* in_sizes, int n_in,
                              void* d_out, int out_size, void* d_ws, size_t ws_size,
                              hipStream_t stream)
{
    const float* x     = (const float*)d_in[0];
    const float* w_off = (const float*)d_in[1];
    const float* w_def = (const float*)d_in[2];
    float* out = (float*)d_out;

    // ws: xtPair[4.19MB] | wPack[1.18MB] | wOffA[147KB] | offPart[1.18MB]
    // total 6,701,056 B  (< round-2-proven 7,077,888 B budget)
    ushort_t* xtP     = (ushort_t*)d_ws;
    ushort_t* wPack   = xtP + (size_t)2 * HW * C;
    ushort_t* wOffA   = wPack + (size_t)NHS * 16 * 64 * 8;
    float*    offPart = (float*)(wOffA + (size_t)NHS * 2 * 64 * 8);

    pack_w<<<(NHS * 16 * 64 + 255) / 256, 256, 0, stream>>>(w_def, wPack);
    pack_woffA<<<(NHS * 2 * 64 + 255) / 256, 256, 0, stream>>>(w_off, wOffA);

    for (int pr = 0; pr < 2; ++pr) {
        transpose_pair<<<512, 256, 0, stream>>>(x, xtP, pr * 2);
        offconv_mfma<<<256, 256, 0, stream>>>(xtP, wOffA, offPart);
        deform_pair<<<512, 256, 0, stream>>>(xtP, offPart, wPack, out, pr * 2);
    }
}